// Round 4
// baseline (317.860 us; speedup 1.0000x reference)
//
#include <hip/hip_runtime.h>

// SobelLoss R4: one output row per thread, all 9 window loads issued up-front.
//
// R3b post-mortem: sliding-window streaming kept only ONE row of lookahead in
// flight (~48B/lane) -> wave stalls on vmcnt every row; HBM stuck at 27%,
// occupancy 40%. This version removes the inter-row dependence chain: each
// thread loads its full 3x3 window (9 independent 16B loads: 3 rows x
// {pred,tgt,mask}) back-to-back with no waits in between (144B/lane in
// flight, ~9KB/wave), computes, stores once. Row re-reads (3x) are L2/L3
// hits; HBM fetch stays ~ideal. Horizontal neighbors via __shfl +/-2 with
// masked edge-lane loads. Grid = 24576 short uniform blocks, XCD-contiguous
// swizzle for L2 row-band locality. Border rows: zero store, early out.
//
// valid = AND of 3x3 mask (== conv(mask,ones)==9); zero-pad borders -> 0.
// Same separable math as R3b (passed absmax 0.03125):
//   d = pred - tgt; hx = dR - dL; hs = dL + 2d + dR (per row)
//   gx = hx(r-1) + 2hx(r) + hx(r+1); gy = hs(r+1) - hs(r-1).

constexpr int H = 512, W = 512, F = 8;
constexpr int IMAGES = 12;               // B*T
constexpr int NB = IMAGES * H * 4;       // 24576 blocks (4 quads of 128 px/row)

typedef float f32x4 __attribute__((ext_vector_type(4)));

__global__ __launch_bounds__(256) void sobel_loss_kernel(
    const float* __restrict__ pred,
    const float* __restrict__ tgt,
    const int*   __restrict__ mask,
    float*       __restrict__ out)
{
    const int tid  = threadIdx.x;
    const int lane = tid & 63;
    const int wid  = tid >> 6;

    // XCD-contiguous bijective swizzle (NB % 8 == 0): each XCD gets a
    // contiguous band of (img,row) work -> halo re-reads stay in its L2.
    const int b0  = blockIdx.x;
    const int bid = (b0 & 7) * (NB >> 3) + (b0 >> 3);

    const int img  = bid >> 11;          // 2048 blocks per image
    const int rest = bid & 2047;
    const int r    = rest >> 2;          // row 0..511
    const int quad = rest & 3;           // 128-pixel quarter of the row

    const int p = lane >> 1;             // pixel within wave's 32-pixel span
    const int q = lane & 1;              // float4 half of the pixel
    const int w = quad * 128 + wid * 32 + p;

    const size_t ibase = (size_t)img * ((size_t)H * W * F);
    const int voff = w * F + q * 4;
    float* const orow = out + ibase + (size_t)r * (W * F) + voff;

    if (r == 0 || r == H - 1) {          // border rows: valid == 0 everywhere
        f32x4 z = {0.f, 0.f, 0.f, 0.f};
        __builtin_nontemporal_store(z, (f32x4*)orow);
        return;
    }

    const bool eL = (p == 0);
    const bool eR = (p == 31);
    const bool edge = eL || eR;
    const int  wn  = eL ? (w > 0 ? w - 1 : 0) : (w < W - 1 ? w + 1 : W - 1);
    const int  eoff = wn * F + q * 4;
    const bool win  = (w > 0) & (w < W - 1);

    const size_t ro0 = ibase + (size_t)(r - 1) * (W * F);
    const size_t ro1 = ibase + (size_t)(r    ) * (W * F);
    const size_t ro2 = ibase + (size_t)(r + 1) * (W * F);

    // ---- 9 primary loads, all independent, issued back-to-back ----
    const float4 P0 = *(const float4*)(pred + ro0 + voff);
    const float4 P1 = *(const float4*)(pred + ro1 + voff);
    const float4 P2 = *(const float4*)(pred + ro2 + voff);
    const float4 T0 = *(const float4*)(tgt  + ro0 + voff);
    const float4 T1 = *(const float4*)(tgt  + ro1 + voff);
    const float4 T2 = *(const float4*)(tgt  + ro2 + voff);
    const int4   M0 = *(const int4*)(mask + ro0 + voff);
    const int4   M1 = *(const int4*)(mask + ro1 + voff);
    const int4   M2 = *(const int4*)(mask + ro2 + voff);

    // ---- edge-lane neighbor loads (4/64 lanes, L2-hot) ----
    float4 EP0, EP1, EP2, ET0, ET1, ET2;
    int4   EM0, EM1, EM2;
    EP0 = EP1 = EP2 = ET0 = ET1 = ET2 = make_float4(0.f, 0.f, 0.f, 0.f);
    EM0 = EM1 = EM2 = make_int4(0, 0, 0, 0);
    if (edge) {
        EP0 = *(const float4*)(pred + ro0 + eoff);
        EP1 = *(const float4*)(pred + ro1 + eoff);
        EP2 = *(const float4*)(pred + ro2 + eoff);
        ET0 = *(const float4*)(tgt  + ro0 + eoff);
        ET1 = *(const float4*)(tgt  + ro1 + eoff);
        ET2 = *(const float4*)(tgt  + ro2 + eoff);
        EM0 = *(const int4*)(mask + ro0 + eoff);
        EM1 = *(const int4*)(mask + ro1 + eoff);
        EM2 = *(const int4*)(mask + ro2 + eoff);
    }

#define SUB4(a, b) make_float4((a).x - (b).x, (a).y - (b).y, (a).z - (b).z, (a).w - (b).w)
#define PACK(M) ((unsigned)((M).x | ((M).y << 1) | ((M).z << 2) | ((M).w << 3)))

    float4 hx0, hx1, hx2, hs0, hs1, hs2;
    unsigned hm0, hm1, hm2;

#define ROWOP(P, T, M, EP, ET, EM, HX, HS, HM)                                \
    {                                                                         \
        const float4 d  = SUB4(P, T);                                         \
        const float4 ed = SUB4(EP, ET);                                       \
        const unsigned m  = PACK(M);                                          \
        const unsigned em = PACK(EM);                                         \
        float4 dl, dr;                                                        \
        dl.x = __shfl_up(d.x, 2);   dl.y = __shfl_up(d.y, 2);                 \
        dl.z = __shfl_up(d.z, 2);   dl.w = __shfl_up(d.w, 2);                 \
        dr.x = __shfl_down(d.x, 2); dr.y = __shfl_down(d.y, 2);               \
        dr.z = __shfl_down(d.z, 2); dr.w = __shfl_down(d.w, 2);               \
        unsigned ml = (unsigned)__shfl_up((int)m, 2);                         \
        unsigned mr = (unsigned)__shfl_down((int)m, 2);                       \
        if (eL) { dl = ed; ml = em; }                                         \
        if (eR) { dr = ed; mr = em; }                                         \
        HX = SUB4(dr, dl);                                                    \
        HS = make_float4(dl.x + 2.f * d.x + dr.x,                             \
                         dl.y + 2.f * d.y + dr.y,                             \
                         dl.z + 2.f * d.z + dr.z,                             \
                         dl.w + 2.f * d.w + dr.w);                            \
        HM = ml & m & mr;                                                     \
    }

    ROWOP(P0, T0, M0, EP0, ET0, EM0, hx0, hs0, hm0)
    ROWOP(P1, T1, M1, EP1, ET1, EM1, hx1, hs1, hm1)
    ROWOP(P2, T2, M2, EP2, ET2, EM2, hx2, hs2, hm2)

#undef ROWOP

    unsigned vm = hm0 & hm1 & hm2;
    if (!win) vm = 0u;

    f32x4 o;
    {
        const float gx = hx0.x + 2.f * hx1.x + hx2.x;
        const float gy = hs2.x - hs0.x;
        o.x = (vm & 1u) ? (fabsf(gx) + fabsf(gy)) : 0.f;
    }
    {
        const float gx = hx0.y + 2.f * hx1.y + hx2.y;
        const float gy = hs2.y - hs0.y;
        o.y = (vm & 2u) ? (fabsf(gx) + fabsf(gy)) : 0.f;
    }
    {
        const float gx = hx0.z + 2.f * hx1.z + hx2.z;
        const float gy = hs2.z - hs0.z;
        o.z = (vm & 4u) ? (fabsf(gx) + fabsf(gy)) : 0.f;
    }
    {
        const float gx = hx0.w + 2.f * hx1.w + hx2.w;
        const float gy = hs2.w - hs0.w;
        o.w = (vm & 8u) ? (fabsf(gx) + fabsf(gy)) : 0.f;
    }

    __builtin_nontemporal_store(o, (f32x4*)orow);

#undef SUB4
#undef PACK
}

extern "C" void kernel_launch(void* const* d_in, const int* in_sizes, int n_in,
                              void* d_out, int out_size, void* d_ws, size_t ws_size,
                              hipStream_t stream) {
    const float* pred = (const float*)d_in[0];
    const float* tgt  = (const float*)d_in[1];
    const int*   mask = (const int*)d_in[2];
    float*       out  = (float*)d_out;

    sobel_loss_kernel<<<NB, 256, 0, stream>>>(pred, tgt, mask, out);
}

// Round 5
// 317.475 us; speedup vs baseline: 1.0012x; 1.0012x over previous
//
#include <hip/hip_runtime.h>

// SobelLoss R5: R4 (one output row/thread, 9+9 window loads) + sched_barrier(0)
// to force all loads in flight.
//
// R4 post-mortem: VGPR_Count=40 proves the compiler serialized the "9
// back-to-back" loads (9 float4 results alone need 36 VGPRs) -> only ~2-3
// loads outstanding per wave -> latency-bound at ~25% HBM, exactly as in
// R2/R3b. Fix: issue ALL loads (center + edge-lane neighbor) in one block,
// then __builtin_amdgcn_sched_barrier(0) so the scheduler cannot sink loads
// past it; allocator must keep ~18 results live (~100 VGPR, capped at 128 by
// __launch_bounds__(256,4)); waitcnts become a descending-vmcnt pipeline.
// Per-wave outstanding bytes: ~2KB -> ~9.5KB.
//
// Math identical to R4 (passed, absmax 0.03125):
//   d = pred - tgt; hx = dR - dL; hs = dL + 2d + dR (per row)
//   gx = hx(r-1) + 2hx(r) + hx(r+1); gy = hs(r+1) - hs(r-1)
//   valid = AND of 3x3 mask; border rows/cols forced 0.

constexpr int H = 512, W = 512, F = 8;
constexpr int IMAGES = 12;               // B*T
constexpr int NB = IMAGES * H * 4;       // 24576 blocks (4 quads of 128 px/row)

typedef float f32x4 __attribute__((ext_vector_type(4)));

__global__ __launch_bounds__(256, 4) void sobel_loss_kernel(
    const float* __restrict__ pred,
    const float* __restrict__ tgt,
    const int*   __restrict__ mask,
    float*       __restrict__ out)
{
    const int tid  = threadIdx.x;
    const int lane = tid & 63;
    const int wid  = tid >> 6;

    // XCD-contiguous bijective swizzle (NB % 8 == 0): each XCD gets a
    // contiguous band of (img,row) work -> halo re-reads stay in its L2.
    const int b0  = blockIdx.x;
    const int bid = (b0 & 7) * (NB >> 3) + (b0 >> 3);

    const int img  = bid >> 11;          // 2048 blocks per image
    const int rest = bid & 2047;
    const int r    = rest >> 2;          // row 0..511
    const int quad = rest & 3;           // 128-pixel quarter of the row

    const int p = lane >> 1;             // pixel within wave's 32-pixel span
    const int q = lane & 1;              // float4 half of the pixel
    const int w = quad * 128 + wid * 32 + p;

    const size_t ibase = (size_t)img * ((size_t)H * W * F);
    const int voff = w * F + q * 4;
    float* const orow = out + ibase + (size_t)r * (W * F) + voff;

    if (r == 0 || r == H - 1) {          // border rows: valid == 0 everywhere
        f32x4 z = {0.f, 0.f, 0.f, 0.f};
        __builtin_nontemporal_store(z, (f32x4*)orow);
        return;
    }

    const bool eL = (p == 0);
    const bool eR = (p == 31);
    const bool edge = eL || eR;
    const int  wn  = eL ? (w > 0 ? w - 1 : 0) : (w < W - 1 ? w + 1 : W - 1);
    const int  eoff = wn * F + q * 4;
    const bool win  = (w > 0) & (w < W - 1);

    const size_t ro0 = ibase + (size_t)(r - 1) * (W * F);
    const size_t ro1 = ibase + (size_t)(r    ) * (W * F);
    const size_t ro2 = ibase + (size_t)(r + 1) * (W * F);

    // ---- 9 primary loads, all independent ----
    const float4 P0 = *(const float4*)(pred + ro0 + voff);
    const float4 P1 = *(const float4*)(pred + ro1 + voff);
    const float4 P2 = *(const float4*)(pred + ro2 + voff);
    const float4 T0 = *(const float4*)(tgt  + ro0 + voff);
    const float4 T1 = *(const float4*)(tgt  + ro1 + voff);
    const float4 T2 = *(const float4*)(tgt  + ro2 + voff);
    const int4   M0 = *(const int4*)(mask + ro0 + voff);
    const int4   M1 = *(const int4*)(mask + ro1 + voff);
    const int4   M2 = *(const int4*)(mask + ro2 + voff);

    // ---- edge-lane neighbor loads (4/64 lanes, L2-hot), same load block ----
    float4 EP0, EP1, EP2, ET0, ET1, ET2;
    int4   EM0, EM1, EM2;
    EP0 = EP1 = EP2 = ET0 = ET1 = ET2 = make_float4(0.f, 0.f, 0.f, 0.f);
    EM0 = EM1 = EM2 = make_int4(0, 0, 0, 0);
    if (edge) {
        EP0 = *(const float4*)(pred + ro0 + eoff);
        EP1 = *(const float4*)(pred + ro1 + eoff);
        EP2 = *(const float4*)(pred + ro2 + eoff);
        ET0 = *(const float4*)(tgt  + ro0 + eoff);
        ET1 = *(const float4*)(tgt  + ro1 + eoff);
        ET2 = *(const float4*)(tgt  + ro2 + eoff);
        EM0 = *(const int4*)(mask + ro0 + eoff);
        EM1 = *(const int4*)(mask + ro1 + eoff);
        EM2 = *(const int4*)(mask + ro2 + eoff);
    }

    // Scheduling fence: nothing below may be hoisted above, no load may be
    // sunk below -> all ~18 loads are issued before any consumer, keeping
    // them simultaneously in flight (the whole point of this revision).
    __builtin_amdgcn_sched_barrier(0);

#define SUB4(a, b) make_float4((a).x - (b).x, (a).y - (b).y, (a).z - (b).z, (a).w - (b).w)
#define PACK(M) ((unsigned)((M).x | ((M).y << 1) | ((M).z << 2) | ((M).w << 3)))

    float4 hx0, hx1, hx2, hs0, hs1, hs2;
    unsigned hm0, hm1, hm2;

#define ROWOP(P, T, M, EP, ET, EM, HX, HS, HM)                                \
    {                                                                         \
        const float4 d  = SUB4(P, T);                                         \
        const float4 ed = SUB4(EP, ET);                                       \
        const unsigned m  = PACK(M);                                          \
        const unsigned em = PACK(EM);                                         \
        float4 dl, dr;                                                        \
        dl.x = __shfl_up(d.x, 2);   dl.y = __shfl_up(d.y, 2);                 \
        dl.z = __shfl_up(d.z, 2);   dl.w = __shfl_up(d.w, 2);                 \
        dr.x = __shfl_down(d.x, 2); dr.y = __shfl_down(d.y, 2);               \
        dr.z = __shfl_down(d.z, 2); dr.w = __shfl_down(d.w, 2);               \
        unsigned ml = (unsigned)__shfl_up((int)m, 2);                         \
        unsigned mr = (unsigned)__shfl_down((int)m, 2);                       \
        if (eL) { dl = ed; ml = em; }                                         \
        if (eR) { dr = ed; mr = em; }                                         \
        HX = SUB4(dr, dl);                                                    \
        HS = make_float4(dl.x + 2.f * d.x + dr.x,                             \
                         dl.y + 2.f * d.y + dr.y,                             \
                         dl.z + 2.f * d.z + dr.z,                             \
                         dl.w + 2.f * d.w + dr.w);                            \
        HM = ml & m & mr;                                                     \
    }

    ROWOP(P0, T0, M0, EP0, ET0, EM0, hx0, hs0, hm0)
    ROWOP(P1, T1, M1, EP1, ET1, EM1, hx1, hs1, hm1)
    ROWOP(P2, T2, M2, EP2, ET2, EM2, hx2, hs2, hm2)

#undef ROWOP

    unsigned vm = hm0 & hm1 & hm2;
    if (!win) vm = 0u;

    f32x4 o;
    {
        const float gx = hx0.x + 2.f * hx1.x + hx2.x;
        const float gy = hs2.x - hs0.x;
        o.x = (vm & 1u) ? (fabsf(gx) + fabsf(gy)) : 0.f;
    }
    {
        const float gx = hx0.y + 2.f * hx1.y + hx2.y;
        const float gy = hs2.y - hs0.y;
        o.y = (vm & 2u) ? (fabsf(gx) + fabsf(gy)) : 0.f;
    }
    {
        const float gx = hx0.z + 2.f * hx1.z + hx2.z;
        const float gy = hs2.z - hs0.z;
        o.z = (vm & 4u) ? (fabsf(gx) + fabsf(gy)) : 0.f;
    }
    {
        const float gx = hx0.w + 2.f * hx1.w + hx2.w;
        const float gy = hs2.w - hs0.w;
        o.w = (vm & 8u) ? (fabsf(gx) + fabsf(gy)) : 0.f;
    }

    __builtin_nontemporal_store(o, (f32x4*)orow);

#undef SUB4
#undef PACK
}

extern "C" void kernel_launch(void* const* d_in, const int* in_sizes, int n_in,
                              void* d_out, int out_size, void* d_ws, size_t ws_size,
                              hipStream_t stream) {
    const float* pred = (const float*)d_in[0];
    const float* tgt  = (const float*)d_in[1];
    const int*   mask = (const int*)d_in[2];
    float*       out  = (float*)d_out;

    sobel_loss_kernel<<<NB, 256, 0, stream>>>(pred, tgt, mask, out);
}

// Round 6
// 314.183 us; speedup vs baseline: 1.0117x; 1.0105x over previous
//
#include <hip/hip_runtime.h>

// SobelLoss R6: wave-per-row streaming stage -> LDS -> local 3x3 compute.
//
// R5 post-mortem: VGPR=40 == 36 load-result regs + addressing, i.e. R4's 9
// loads WERE already in flight; MLP was never the limiter. Limiter is L1/L2
// request-path volume & stream shape: R4 issued 906MB of L1-level reads as
// scattered 1KB bursts. R6: each wave stages ONE row as contiguous 4KB runs
// per array (4 x dwordx4 at base + k*1024 + lane*16 -> every instruction is a
// wave-contiguous 1KB burst), d=p-t in regs, lane-contiguous LDS writes
// (conflict-free, no div/mod). 8 staged rows -> 6 output rows per block
// (reuse overhead 1.33x, L1 reads ~406MB). One barrier. Compute is contiguous
// ds_read_b128. LDS 37.4KB -> 4 blocks/CU. Strip-consecutive XCD swizzle.
//
// Math (verified in R2..R5, absmax 0.03125):
//   d = pred - tgt; per row: hx = dR - dL, hs = dL + 2d + dR
//   gx = hx(r-1)+2hx(r)+hx(r+1); gy = hs(r+1)-hs(r-1)
//   valid = AND of 3x3 mask; OOB (borders) contribute mask=0 -> output 0.

constexpr int H = 512, W = 512, F = 8;
constexpr int IMAGES = 12;                 // B*T
constexpr int SPAN  = 128;                 // pixels per block span
constexpr int NSPAN = W / SPAN;            // 4
constexpr int ORWS  = 6;                   // output rows per block
constexpr int SRWS  = 8;                   // staged rows (halo 2)
constexpr int STRIPS = (H + ORWS - 1) / ORWS;   // 86
constexpr int NB = IMAGES * NSPAN * STRIPS;     // 4128 (div by 8)
constexpr int UROW = 2 * SPAN + 4;         // 260 16B-units per staged row

typedef float f32x4 __attribute__((ext_vector_type(4)));

__global__ __launch_bounds__(512) void sobel_loss_kernel(
    const float* __restrict__ pred,
    const float* __restrict__ tgt,
    const int*   __restrict__ mask,
    float*       __restrict__ out)
{
    __shared__ float4         dls[SRWS * UROW];   // 33,280 B
    __shared__ unsigned short mls[SRWS * UROW];   //  4,160 B

    const int tid  = threadIdx.x;
    const int l    = tid & 63;
    const int wv   = tid >> 6;                 // wave = staged row index 0..7

    // XCD-contiguous bijective swizzle (NB % 8 == 0). Consecutive bid ->
    // consecutive strips (vertically adjacent) -> halo rows L2-local per XCD.
    const int b0  = blockIdx.x;
    const int bid = (b0 & 7) * (NB >> 3) + (b0 >> 3);

    const int img   = bid / (NSPAN * STRIPS);
    const int rest  = bid - img * (NSPAN * STRIPS);
    const int span  = rest / STRIPS;
    const int strip = rest - span * STRIPS;

    const int r0 = strip * ORWS;               // first output row
    const int w0 = span * SPAN;                // first pixel of span

    const size_t ibase = (size_t)img * ((size_t)H * W * F);

    // ---------------- stage phase: wave wv stages global row r0-1+wv -------
    {
        const int gr  = r0 - 1 + wv;
        const int grc = gr < 0 ? 0 : (gr >= H ? H - 1 : gr);
        const bool rv = (gr >= 0) & (gr < H);
        const size_t rowf = ibase + (size_t)grc * (W * F) + (size_t)w0 * F;

        // main span: 4 contiguous 1KB wave-bursts per array
        float4 P[4], T[4]; int4 M[4];
#pragma unroll
        for (int k = 0; k < 4; ++k) {
            const size_t o = rowf + (size_t)k * 256 + l * 4;  // floats
            P[k] = *(const float4*)(pred + o);
            T[k] = *(const float4*)(tgt  + o);
            M[k] = *(const int4*)(mask + o);
        }

        // edge halo: lanes 0..3 load (px = w0-1 | w0+128) x (q=0,1)
        float4 EP = make_float4(0.f,0.f,0.f,0.f), ET = EP;
        int4   EM = make_int4(0,0,0,0);
        const bool left = (l < 2);
        const int  qe   = l & 1;
        const int  pxg  = left ? (w0 - 1) : (w0 + SPAN);
        const bool ib   = (pxg >= 0) & (pxg < W);
        if (l < 4) {
            const int pxc = ib ? pxg : 0;
            const size_t o = ibase + (size_t)grc * (W * F) + (size_t)pxc * F + qe * 4;
            EP = *(const float4*)(pred + o);
            ET = *(const float4*)(tgt  + o);
            EM = *(const int4*)(mask + o);
        }

        float4* drow = dls + wv * UROW;
        unsigned short* mrow = mls + wv * UROW;
#pragma unroll
        for (int k = 0; k < 4; ++k) {
            const int u = 2 + k * 64 + l;      // lane-contiguous 16B units
            drow[u] = make_float4(P[k].x - T[k].x, P[k].y - T[k].y,
                                  P[k].z - T[k].z, P[k].w - T[k].w);
            const unsigned bits = (unsigned)(M[k].x | (M[k].y << 1) |
                                             (M[k].z << 2) | (M[k].w << 3));
            mrow[u] = (unsigned short)(rv ? bits : 0u);
        }
        if (l < 4) {
            const int u = left ? qe : (2 + 2 * SPAN + qe);   // units 0,1 / 258,259
            drow[u] = make_float4(EP.x - ET.x, EP.y - ET.y,
                                  EP.z - ET.z, EP.w - ET.w);
            const unsigned bits = (unsigned)(EM.x | (EM.y << 1) |
                                             (EM.z << 2) | (EM.w << 3));
            mrow[u] = (unsigned short)((rv && ib) ? bits : 0u);
        }
    }

    __syncthreads();

    // ---------------- compute phase: 3 output units per thread -------------
#pragma unroll
    for (int pass = 0; pass < 3; ++pass) {
        const int ot = tid + pass * 512;       // 0..1535
        const int ol = ot >> 8;                // output row in block 0..5
        const int uo = ot & 255;               // unit within row
        const int ro = r0 + ol;                // global output row
        if (ro < H) {
            const int bc = (ol + 1) * UROW + 2 + uo;   // center-row own unit

            // row r-1
            const float4 a0 = dls[bc - UROW - 2];
            const float4 a1 = dls[bc - UROW];
            const float4 a2 = dls[bc - UROW + 2];
            const unsigned mA = (unsigned)mls[bc - UROW - 2] &
                                (unsigned)mls[bc - UROW] &
                                (unsigned)mls[bc - UROW + 2];
            // row r
            const float4 b0r = dls[bc - 2];
            const float4 b1r = dls[bc];
            const float4 b2r = dls[bc + 2];
            const unsigned mB = (unsigned)mls[bc - 2] &
                                (unsigned)mls[bc] &
                                (unsigned)mls[bc + 2];
            // row r+1
            const float4 c0 = dls[bc + UROW - 2];
            const float4 c1 = dls[bc + UROW];
            const float4 c2 = dls[bc + UROW + 2];
            const unsigned mC = (unsigned)mls[bc + UROW - 2] &
                                (unsigned)mls[bc + UROW] &
                                (unsigned)mls[bc + UROW + 2];

            const unsigned vm = mA & mB & mC;

            f32x4 o;
#define COMP(cc, bit)                                                          \
            {                                                                  \
                const float hx0 = a2.cc - a0.cc;                               \
                const float hx1 = b2r.cc - b0r.cc;                             \
                const float hx2 = c2.cc - c0.cc;                               \
                const float hs0 = a0.cc + 2.f * a1.cc + a2.cc;                 \
                const float hs2 = c0.cc + 2.f * c1.cc + c2.cc;                 \
                const float gx = hx0 + 2.f * hx1 + hx2;                        \
                const float gy = hs2 - hs0;                                    \
                o.cc = (vm & (1u << bit)) ? (fabsf(gx) + fabsf(gy)) : 0.f;     \
            }
            COMP(x, 0) COMP(y, 1) COMP(z, 2) COMP(w, 3)
#undef COMP

            float* const op = out + ibase + ((size_t)ro * W + w0) * F + uo * 4;
            __builtin_nontemporal_store(o, (f32x4*)op);
        }
    }
}

extern "C" void kernel_launch(void* const* d_in, const int* in_sizes, int n_in,
                              void* d_out, int out_size, void* d_ws, size_t ws_size,
                              hipStream_t stream) {
    const float* pred = (const float*)d_in[0];
    const float* tgt  = (const float*)d_in[1];
    const int*   mask = (const int*)d_in[2];
    float*       out  = (float*)d_out;

    sobel_loss_kernel<<<NB, 512, 0, stream>>>(pred, tgt, mask, out);
}